// Round 3
// baseline (693.109 us; speedup 1.0000x reference)
//
#include <hip/hip_runtime.h>

// ---------------------------------------------------------------------------
// CrossAttention: out = mean_h softmax(softmax((x@Wq)/4 · K^T + v) * exp(cur))
// B=4096, IN=1024, H=16, E=256, N_EP=2048.
// Strategy: bf16 hi/lo split (3-pass MFMA) for fp32-class accuracy.
// k_attn v2: tiled K layout + register prefetch pipeline + conflict-free LDS.
// ---------------------------------------------------------------------------

typedef __attribute__((ext_vector_type(8))) short bf16x8;
typedef __attribute__((ext_vector_type(4))) float f32x4;

typedef const __attribute__((address_space(1))) void* gcptr;
typedef __attribute__((address_space(3))) void* sptr;

__device__ __forceinline__ void gload16(const void* g, void* l) {
  __builtin_amdgcn_global_load_lds((gcptr)g, (sptr)l, 16, 0, 0);
}

// round-to-nearest-even fp32 -> bf16 (bit-level)
__device__ __forceinline__ unsigned short f2bf(float f) {
  unsigned int u = __float_as_uint(f);
  unsigned int r = (u + 0x7fffu + ((u >> 16) & 1u)) >> 16;
  return (unsigned short)r;
}
__device__ __forceinline__ float bf2f(unsigned short s) {
  return __uint_as_float(((unsigned int)s) << 16);
}

// ------------------------- elementwise split (x) ---------------------------
__global__ void k_split(const float* __restrict__ src,
                        unsigned short* __restrict__ hi,
                        unsigned short* __restrict__ lo, int n4) {
  int i = blockIdx.x * blockDim.x + threadIdx.x;
  if (i >= n4) return;
  float4 v = reinterpret_cast<const float4*>(src)[i];
  ushort4 h, l;
  h.x = f2bf(v.x); l.x = f2bf(v.x - bf2f(h.x));
  h.y = f2bf(v.y); l.y = f2bf(v.y - bf2f(h.y));
  h.z = f2bf(v.z); l.z = f2bf(v.z - bf2f(h.z));
  h.w = f2bf(v.w); l.w = f2bf(v.w - bf2f(h.w));
  reinterpret_cast<ushort4*>(hi)[i] = h;
  reinterpret_cast<ushort4*>(lo)[i] = l;
}

// ---- K prep: split + retile into MFMA-fragment order ----------------------
// K_t layout (per plane): [jg(128)][k0(8)][lane(64)][8 shorts]
//   lane lam <-> (row = jg*16 + (lam&15), col = k0*32 + (lam>>4)*8)
// so a wave's B-frag load for (jg,k0) is one contiguous 1KB dwordx4 stream.
__global__ void k_prepk(const float* __restrict__ keys,
                        unsigned short* __restrict__ th,
                        unsigned short* __restrict__ tl) {
  int g = blockIdx.x * blockDim.x + threadIdx.x;  // 65536 chunks of 8 elems
  int jg = g >> 9, rem = g & 511;
  int k0 = rem >> 6, lam = rem & 63;
  int row = jg * 16 + (lam & 15);
  int col = k0 * 32 + (lam >> 4) * 8;
  const float* s = keys + (size_t)row * 256 + col;
  float4 v0 = *reinterpret_cast<const float4*>(s);
  float4 v1 = *reinterpret_cast<const float4*>(s + 4);
  ushort4 h0, h1, l0, l1;
  h0.x = f2bf(v0.x); l0.x = f2bf(v0.x - bf2f(h0.x));
  h0.y = f2bf(v0.y); l0.y = f2bf(v0.y - bf2f(h0.y));
  h0.z = f2bf(v0.z); l0.z = f2bf(v0.z - bf2f(h0.z));
  h0.w = f2bf(v0.w); l0.w = f2bf(v0.w - bf2f(h0.w));
  h1.x = f2bf(v1.x); l1.x = f2bf(v1.x - bf2f(h1.x));
  h1.y = f2bf(v1.y); l1.y = f2bf(v1.y - bf2f(h1.y));
  h1.z = f2bf(v1.z); l1.z = f2bf(v1.z - bf2f(h1.z));
  h1.w = f2bf(v1.w); l1.w = f2bf(v1.w - bf2f(h1.w));
  reinterpret_cast<ushort4*>(th + (size_t)g * 8)[0] = h0;
  reinterpret_cast<ushort4*>(th + (size_t)g * 8)[1] = h1;
  reinterpret_cast<ushort4*>(tl + (size_t)g * 8)[0] = l0;
  reinterpret_cast<ushort4*>(tl + (size_t)g * 8)[1] = l1;
}

// ---------------- transpose + split Wq [1024,4096] -> WqT [4096,1024] ------
__global__ void k_twq(const float* __restrict__ W,
                      unsigned short* __restrict__ th,
                      unsigned short* __restrict__ tl) {
  __shared__ float t[64][65];
  int tx = threadIdx.x & 63, ty = threadIdx.x >> 6;
  int c0 = blockIdx.x * 64, r0 = blockIdx.y * 64;
#pragma unroll
  for (int i = 0; i < 64; i += 4)
    t[ty + i][tx] = W[(size_t)(r0 + ty + i) * 4096 + (c0 + tx)] * 0.25f;
  __syncthreads();
#pragma unroll
  for (int i = 0; i < 64; i += 4) {
    float v = t[tx][ty + i];
    unsigned short h = f2bf(v);
    unsigned short l = f2bf(v - bf2f(h));
    size_t o = (size_t)(c0 + ty + i) * 1024 + (r0 + tx);
    th[o] = h; tl[o] = l;
  }
}

// ------------------- GEMM1: q = x @ WqT', both [.,K] row-major -------------
__global__ __launch_bounds__(256) void k_gemm1(
    const unsigned short* __restrict__ Ah, const unsigned short* __restrict__ Al,
    const unsigned short* __restrict__ Bh, const unsigned short* __restrict__ Bl,
    unsigned short* __restrict__ Qh, unsigned short* __restrict__ Ql) {
  __shared__ unsigned short As[2][128][32];
  __shared__ unsigned short Bs[2][128][32];
  const int tid = threadIdx.x;
  const int w = tid >> 6, l = tid & 63;
  const int lr = l & 15, lg = l >> 4;
  const int m0 = blockIdx.y * 128, n0 = blockIdx.x * 128;
  const int wr = (w >> 1) * 64, wc = (w & 1) * 64;
  const int srow = tid >> 2;
  const int skel = (tid & 3) * 8;
  f32x4 acc[4][4] = {};

  const size_t gaBase = (size_t)(m0 + srow) * 1024 + skel;
  const size_t gbBase = (size_t)(n0 + srow) * 1024 + skel;
  char* lA0 = (char*)&As[0][0][0] + w * 1024;
  char* lA1 = (char*)&As[1][0][0] + w * 1024;
  char* lB0 = (char*)&Bs[0][0][0] + w * 1024;
  char* lB1 = (char*)&Bs[1][0][0] + w * 1024;

  for (int k0 = 0; k0 < 1024; k0 += 32) {
    gload16(Ah + gaBase + k0,             lA0);
    gload16(Ah + gaBase + 64 * 1024 + k0, lA0 + 4096);
    gload16(Al + gaBase + k0,             lA1);
    gload16(Al + gaBase + 64 * 1024 + k0, lA1 + 4096);
    gload16(Bh + gbBase + k0,             lB0);
    gload16(Bh + gbBase + 64 * 1024 + k0, lB0 + 4096);
    gload16(Bl + gbBase + k0,             lB1);
    gload16(Bl + gbBase + 64 * 1024 + k0, lB1 + 4096);
    __syncthreads();
    bf16x8 ah[4], am[4], bh[4], bm[4];
#pragma unroll
    for (int i = 0; i < 4; ++i) {
      ah[i] = *reinterpret_cast<const bf16x8*>(&As[0][wr + i * 16 + lr][lg * 8]);
      am[i] = *reinterpret_cast<const bf16x8*>(&As[1][wr + i * 16 + lr][lg * 8]);
      bh[i] = *reinterpret_cast<const bf16x8*>(&Bs[0][wc + i * 16 + lr][lg * 8]);
      bm[i] = *reinterpret_cast<const bf16x8*>(&Bs[1][wc + i * 16 + lr][lg * 8]);
    }
#pragma unroll
    for (int i = 0; i < 4; ++i)
#pragma unroll
      for (int j = 0; j < 4; ++j) {
        acc[i][j] = __builtin_amdgcn_mfma_f32_16x16x32_bf16(ah[i], bh[j], acc[i][j], 0, 0, 0);
        acc[i][j] = __builtin_amdgcn_mfma_f32_16x16x32_bf16(am[i], bh[j], acc[i][j], 0, 0, 0);
        acc[i][j] = __builtin_amdgcn_mfma_f32_16x16x32_bf16(ah[i], bm[j], acc[i][j], 0, 0, 0);
      }
    __syncthreads();
  }
#pragma unroll
  for (int i = 0; i < 4; ++i)
#pragma unroll
    for (int j = 0; j < 4; ++j)
#pragma unroll
      for (int r = 0; r < 4; ++r) {
        int row = m0 + wr + i * 16 + lg * 4 + r;
        int col = n0 + wc + j * 16 + lr;
        float v = acc[i][j][r];
        unsigned short hh = f2bf(v);
        unsigned short ll = f2bf(v - bf2f(hh));
        size_t o = (size_t)row * 4096 + col;
        Qh[o] = hh; Ql[o] = ll;
      }
}

// ---- fused GEMM2 + double softmax + head-mean (v2) -------------------------
// block: 512 thr (8 waves), 32 q2-rows, full N=2048; wave w owns cols
// [w*256, w*256+256). q in frag-major LDS (conflict-free ds_read_b128);
// K streamed from tiled global layout with a depth-4 register prefetch
// pipeline; NO barriers inside the 8x16-iteration K loop.
__global__ __launch_bounds__(512, 2) void k_attn(
    const unsigned short* __restrict__ Qh, const unsigned short* __restrict__ Ql,
    const unsigned short* __restrict__ KtH, const unsigned short* __restrict__ KtL,
    const float* __restrict__ values, const float* __restrict__ cur,
    float* __restrict__ out) {
  // slot s = plane*16 + mf*8 + k0; each slot: 64 lanes x 16B, lane-linear
  __shared__ unsigned short As[32 * 512];   // 32 KiB
  __shared__ float red[8][32];
  const int tid = threadIdx.x;
  const int w = tid >> 6, l = tid & 63;
  const int lr = l & 15, lg = l >> 4;
  const int r0 = blockIdx.x * 32;   // q2 row base
  const int n0 = w * 256;           // wave col-slice

  // ---- stage q rows (hi+lo) into frag-major LDS; wave w does slots w*4..+3
#pragma unroll
  for (int qq = 0; qq < 4; ++qq) {
    const int s = w * 4 + qq;
    const int plane = s >> 4, mf = (s >> 3) & 1, k0s = s & 7;
    const unsigned short* src = plane ? Ql : Qh;
    const size_t ga = (size_t)(r0 + mf * 16 + lr) * 256 + k0s * 32 + lg * 8;
    gload16(src + ga, (char*)As + s * 1024);
  }
  __syncthreads();

  // wave-local K base (tiled layout, + per-lane 16B)
  const unsigned short* kwH = KtH + (size_t)w * 16 * 8 * 512 + (size_t)l * 8;
  const unsigned short* kwL = KtL + (size_t)w * 16 * 8 * 512 + (size_t)l * 8;

  f32x4 acc[2][16] = {};
  bf16x8 kh[4], kl[4];
  // prologue: prefetch (k0=0, j=0..3)
#pragma unroll
  for (int j = 0; j < 4; ++j) {
    kh[j] = *reinterpret_cast<const bf16x8*>(kwH + (size_t)j * 4096);
    kl[j] = *reinterpret_cast<const bf16x8*>(kwL + (size_t)j * 4096);
  }

  for (int k0 = 0; k0 < 8; ++k0) {
    bf16x8 ah[2], am[2];
#pragma unroll
    for (int mf = 0; mf < 2; ++mf) {
      ah[mf] = *reinterpret_cast<const bf16x8*>(As + (size_t)(mf * 8 + k0) * 512 + l * 8);
      am[mf] = *reinterpret_cast<const bf16x8*>(As + (size_t)(16 + mf * 8 + k0) * 512 + l * 8);
    }
    const unsigned short* pHc = kwH + (size_t)k0 * 512;
    const unsigned short* pLc = kwL + (size_t)k0 * 512;
#pragma unroll
    for (int j = 0; j < 16; ++j) {
      const int sl = j & 3;
      // compute with current slot
      acc[0][j] = __builtin_amdgcn_mfma_f32_16x16x32_bf16(ah[0], kh[sl], acc[0][j], 0, 0, 0);
      acc[1][j] = __builtin_amdgcn_mfma_f32_16x16x32_bf16(ah[1], kh[sl], acc[1][j], 0, 0, 0);
      acc[0][j] = __builtin_amdgcn_mfma_f32_16x16x32_bf16(am[0], kh[sl], acc[0][j], 0, 0, 0);
      acc[1][j] = __builtin_amdgcn_mfma_f32_16x16x32_bf16(am[1], kh[sl], acc[1][j], 0, 0, 0);
      acc[0][j] = __builtin_amdgcn_mfma_f32_16x16x32_bf16(ah[0], kl[sl], acc[0][j], 0, 0, 0);
      acc[1][j] = __builtin_amdgcn_mfma_f32_16x16x32_bf16(ah[1], kl[sl], acc[1][j], 0, 0, 0);
      // prefetch t+4 into this slot
      if (j < 12) {
        const int jj = j + 4;
        kh[sl] = *reinterpret_cast<const bf16x8*>(pHc + (size_t)jj * 4096);
        kl[sl] = *reinterpret_cast<const bf16x8*>(pLc + (size_t)jj * 4096);
      } else if (k0 < 7) {
        const int jj = j - 12;
        kh[sl] = *reinterpret_cast<const bf16x8*>(pHc + 512 + (size_t)jj * 4096);
        kl[sl] = *reinterpret_cast<const bf16x8*>(pLc + 512 + (size_t)jj * 4096);
      }
    }
  }

  // logits = acc + values[n]
#pragma unroll
  for (int j = 0; j < 16; ++j) {
    float vv = values[n0 + j * 16 + lr];
#pragma unroll
    for (int mf = 0; mf < 2; ++mf)
#pragma unroll
      for (int r = 0; r < 4; ++r) acc[mf][j][r] += vv;
  }

  const int rb = lg * 4;
  // ---------------- first softmax: row max ----------------
  float M1[2][4];
#pragma unroll
  for (int mf = 0; mf < 2; ++mf)
#pragma unroll
    for (int r = 0; r < 4; ++r) {
      float m = acc[mf][0][r];
#pragma unroll
      for (int j = 1; j < 16; ++j) m = fmaxf(m, acc[mf][j][r]);
      m = fmaxf(m, __shfl_xor(m, 1));
      m = fmaxf(m, __shfl_xor(m, 2));
      m = fmaxf(m, __shfl_xor(m, 4));
      m = fmaxf(m, __shfl_xor(m, 8));
      M1[mf][r] = m;
    }
  if (lr == 0) {
#pragma unroll
    for (int mf = 0; mf < 2; ++mf)
#pragma unroll
      for (int r = 0; r < 4; ++r) red[w][mf * 16 + rb + r] = M1[mf][r];
  }
  __syncthreads();
#pragma unroll
  for (int mf = 0; mf < 2; ++mf)
#pragma unroll
    for (int r = 0; r < 4; ++r) {
      float m = red[0][mf * 16 + rb + r];
#pragma unroll
      for (int w2 = 1; w2 < 8; ++w2) m = fmaxf(m, red[w2][mf * 16 + rb + r]);
      M1[mf][r] = m;
    }
  __syncthreads();
  // ---------------- e1 = exp(l - M1), Z1 ----------------
  float Z1[2][4];
#pragma unroll
  for (int mf = 0; mf < 2; ++mf)
#pragma unroll
    for (int r = 0; r < 4; ++r) {
      float z = 0.f;
#pragma unroll
      for (int j = 0; j < 16; ++j) {
        float e = __expf(acc[mf][j][r] - M1[mf][r]);
        acc[mf][j][r] = e;
        z += e;
      }
      z += __shfl_xor(z, 1); z += __shfl_xor(z, 2);
      z += __shfl_xor(z, 4); z += __shfl_xor(z, 8);
      Z1[mf][r] = z;
    }
  if (lr == 0) {
#pragma unroll
    for (int mf = 0; mf < 2; ++mf)
#pragma unroll
      for (int r = 0; r < 4; ++r) red[w][mf * 16 + rb + r] = Z1[mf][r];
  }
  __syncthreads();
#pragma unroll
  for (int mf = 0; mf < 2; ++mf)
#pragma unroll
    for (int r = 0; r < 4; ++r) {
      float z = 0.f;
#pragma unroll
      for (int w2 = 0; w2 < 8; ++w2) z += red[w2][mf * 16 + rb + r];
      Z1[mf][r] = z;
    }
  __syncthreads();
  // ---------------- second softmax (max(logits2) = c/Z1 exactly) -----------
  const float c0 = __expf(cur[(r0 >> 4) + 0]);
  const float c1 = __expf(cur[(r0 >> 4) + 1]);
  float Z2[2][4];
#pragma unroll
  for (int mf = 0; mf < 2; ++mf)
#pragma unroll
    for (int r = 0; r < 4; ++r) {
      float s2 = (mf ? c1 : c0) / Z1[mf][r];
      float z = 0.f;
#pragma unroll
      for (int j = 0; j < 16; ++j) {
        float o = __expf(s2 * (acc[mf][j][r] - 1.0f));
        acc[mf][j][r] = o;
        z += o;
      }
      z += __shfl_xor(z, 1); z += __shfl_xor(z, 2);
      z += __shfl_xor(z, 4); z += __shfl_xor(z, 8);
      Z2[mf][r] = z;
    }
  if (lr == 0) {
#pragma unroll
    for (int mf = 0; mf < 2; ++mf)
#pragma unroll
      for (int r = 0; r < 4; ++r) red[w][mf * 16 + rb + r] = Z2[mf][r];
  }
  __syncthreads();
#pragma unroll
  for (int mf = 0; mf < 2; ++mf)
#pragma unroll
    for (int r = 0; r < 4; ++r) {
      float z = 0.f;
#pragma unroll
      for (int w2 = 0; w2 < 8; ++w2) z += red[w2][mf * 16 + rb + r];
      Z2[mf][r] = z;
    }
  // ---------------- head-mean + write ----------------
  float rz[2][4];
#pragma unroll
  for (int mf = 0; mf < 2; ++mf)
#pragma unroll
    for (int r = 0; r < 4; ++r) rz[mf][r] = 1.0f / (16.0f * Z2[mf][r]);
#pragma unroll
  for (int mf = 0; mf < 2; ++mf)
#pragma unroll
    for (int j = 0; j < 16; ++j) {
      float s = acc[mf][j][0] * rz[mf][0] + acc[mf][j][1] * rz[mf][1] +
                acc[mf][j][2] * rz[mf][2] + acc[mf][j][3] * rz[mf][3];
      s += __shfl_xor(s, 16);
      s += __shfl_xor(s, 32);
      if (l < 16)
        out[(size_t)((r0 >> 4) + mf) * 2048 + n0 + j * 16 + l] = s;
    }
}

// ---------------------------------------------------------------------------
extern "C" void kernel_launch(void* const* d_in, const int* in_sizes, int n_in,
                              void* d_out, int out_size, void* d_ws, size_t ws_size,
                              hipStream_t stream) {
  const float* x    = (const float*)d_in[0];
  const float* cur  = (const float*)d_in[1];
  const float* Wq   = (const float*)d_in[2];
  const float* keys = (const float*)d_in[3];
  const float* vals = (const float*)d_in[4];
  float* out = (float*)d_out;

  char* ws = (char*)d_ws;
  unsigned short* x_hi = (unsigned short*)ws;  ws += (size_t)4096 * 1024 * 2;
  unsigned short* x_lo = (unsigned short*)ws;  ws += (size_t)4096 * 1024 * 2;
  unsigned short* w_hi = (unsigned short*)ws;  ws += (size_t)4096 * 1024 * 2;
  unsigned short* w_lo = (unsigned short*)ws;  ws += (size_t)4096 * 1024 * 2;
  unsigned short* k_hi = (unsigned short*)ws;  ws += (size_t)2048 * 256 * 2;
  unsigned short* k_lo = (unsigned short*)ws;  ws += (size_t)2048 * 256 * 2;
  unsigned short* q_hi = (unsigned short*)ws;  ws += (size_t)4096 * 4096 * 2;
  unsigned short* q_lo = (unsigned short*)ws;

  k_split<<<4096, 256, 0, stream>>>(x, x_hi, x_lo, 4096 * 1024 / 4);
  k_prepk<<<256, 256, 0, stream>>>(keys, k_hi, k_lo);
  k_twq<<<dim3(64, 16), 256, 0, stream>>>(Wq, w_hi, w_lo);
  k_gemm1<<<dim3(32, 32), 256, 0, stream>>>(x_hi, x_lo, w_hi, w_lo, q_hi, q_lo);
  k_attn<<<2048, 512, 0, stream>>>(q_hi, q_lo, k_hi, k_lo, vals, cur, out);
}

// Round 4
// 399.845 us; speedup vs baseline: 1.7334x; 1.7334x over previous
//
#include <hip/hip_runtime.h>

// ---------------------------------------------------------------------------
// CrossAttention: out = mean_h softmax(softmax((x@Wq)/4 · K^T + v) * exp(cur))
// B=4096, IN=1024, H=16, E=256, N_EP=2048.
// Strategy: bf16 hi/lo split (3-pass MFMA) for fp32-class accuracy.
// k_attn v3: hand-named register prefetch slots (no runtime-indexed arrays
//            -> no scratch), depth-4 pipeline, conflict-free LDS.
// ---------------------------------------------------------------------------

typedef __attribute__((ext_vector_type(8))) short bf16x8;
typedef __attribute__((ext_vector_type(4))) float f32x4;

typedef const __attribute__((address_space(1))) void* gcptr;
typedef __attribute__((address_space(3))) void* sptr;

__device__ __forceinline__ void gload16(const void* g, void* l) {
  __builtin_amdgcn_global_load_lds((gcptr)g, (sptr)l, 16, 0, 0);
}

// round-to-nearest-even fp32 -> bf16 (bit-level)
__device__ __forceinline__ unsigned short f2bf(float f) {
  unsigned int u = __float_as_uint(f);
  unsigned int r = (u + 0x7fffu + ((u >> 16) & 1u)) >> 16;
  return (unsigned short)r;
}
__device__ __forceinline__ float bf2f(unsigned short s) {
  return __uint_as_float(((unsigned int)s) << 16);
}

// ------------------------- elementwise split (x) ---------------------------
__global__ void k_split(const float* __restrict__ src,
                        unsigned short* __restrict__ hi,
                        unsigned short* __restrict__ lo, int n4) {
  int i = blockIdx.x * blockDim.x + threadIdx.x;
  if (i >= n4) return;
  float4 v = reinterpret_cast<const float4*>(src)[i];
  ushort4 h, l;
  h.x = f2bf(v.x); l.x = f2bf(v.x - bf2f(h.x));
  h.y = f2bf(v.y); l.y = f2bf(v.y - bf2f(h.y));
  h.z = f2bf(v.z); l.z = f2bf(v.z - bf2f(h.z));
  h.w = f2bf(v.w); l.w = f2bf(v.w - bf2f(h.w));
  reinterpret_cast<ushort4*>(hi)[i] = h;
  reinterpret_cast<ushort4*>(lo)[i] = l;
}

// ---- K prep: split + retile into MFMA-fragment order ----------------------
// K_t layout (per plane): [jg(128)][k0(8)][lane(64)][8 shorts]
//   lane lam <-> (row = jg*16 + (lam&15), col = k0*32 + (lam>>4)*8)
__global__ void k_prepk(const float* __restrict__ keys,
                        unsigned short* __restrict__ th,
                        unsigned short* __restrict__ tl) {
  int g = blockIdx.x * blockDim.x + threadIdx.x;  // 65536 chunks of 8 elems
  int jg = g >> 9, rem = g & 511;
  int k0 = rem >> 6, lam = rem & 63;
  int row = jg * 16 + (lam & 15);
  int col = k0 * 32 + (lam >> 4) * 8;
  const float* s = keys + (size_t)row * 256 + col;
  float4 v0 = *reinterpret_cast<const float4*>(s);
  float4 v1 = *reinterpret_cast<const float4*>(s + 4);
  ushort4 h0, h1, l0, l1;
  h0.x = f2bf(v0.x); l0.x = f2bf(v0.x - bf2f(h0.x));
  h0.y = f2bf(v0.y); l0.y = f2bf(v0.y - bf2f(h0.y));
  h0.z = f2bf(v0.z); l0.z = f2bf(v0.z - bf2f(h0.z));
  h0.w = f2bf(v0.w); l0.w = f2bf(v0.w - bf2f(h0.w));
  h1.x = f2bf(v1.x); l1.x = f2bf(v1.x - bf2f(h1.x));
  h1.y = f2bf(v1.y); l1.y = f2bf(v1.y - bf2f(h1.y));
  h1.z = f2bf(v1.z); l1.z = f2bf(v1.z - bf2f(h1.z));
  h1.w = f2bf(v1.w); l1.w = f2bf(v1.w - bf2f(h1.w));
  reinterpret_cast<ushort4*>(th + (size_t)g * 8)[0] = h0;
  reinterpret_cast<ushort4*>(th + (size_t)g * 8)[1] = h1;
  reinterpret_cast<ushort4*>(tl + (size_t)g * 8)[0] = l0;
  reinterpret_cast<ushort4*>(tl + (size_t)g * 8)[1] = l1;
}

// ---------------- transpose + split Wq [1024,4096] -> WqT [4096,1024] ------
__global__ void k_twq(const float* __restrict__ W,
                      unsigned short* __restrict__ th,
                      unsigned short* __restrict__ tl) {
  __shared__ float t[64][65];
  int tx = threadIdx.x & 63, ty = threadIdx.x >> 6;
  int c0 = blockIdx.x * 64, r0 = blockIdx.y * 64;
#pragma unroll
  for (int i = 0; i < 64; i += 4)
    t[ty + i][tx] = W[(size_t)(r0 + ty + i) * 4096 + (c0 + tx)] * 0.25f;
  __syncthreads();
#pragma unroll
  for (int i = 0; i < 64; i += 4) {
    float v = t[tx][ty + i];
    unsigned short h = f2bf(v);
    unsigned short l = f2bf(v - bf2f(h));
    size_t o = (size_t)(c0 + ty + i) * 1024 + (r0 + tx);
    th[o] = h; tl[o] = l;
  }
}

// ------------------- GEMM1: q = x @ WqT', both [.,K] row-major -------------
__global__ __launch_bounds__(256) void k_gemm1(
    const unsigned short* __restrict__ Ah, const unsigned short* __restrict__ Al,
    const unsigned short* __restrict__ Bh, const unsigned short* __restrict__ Bl,
    unsigned short* __restrict__ Qh, unsigned short* __restrict__ Ql) {
  __shared__ unsigned short As[2][128][32];
  __shared__ unsigned short Bs[2][128][32];
  const int tid = threadIdx.x;
  const int w = tid >> 6, l = tid & 63;
  const int lr = l & 15, lg = l >> 4;
  const int m0 = blockIdx.y * 128, n0 = blockIdx.x * 128;
  const int wr = (w >> 1) * 64, wc = (w & 1) * 64;
  const int srow = tid >> 2;
  const int skel = (tid & 3) * 8;
  f32x4 acc[4][4] = {};

  const size_t gaBase = (size_t)(m0 + srow) * 1024 + skel;
  const size_t gbBase = (size_t)(n0 + srow) * 1024 + skel;
  char* lA0 = (char*)&As[0][0][0] + w * 1024;
  char* lA1 = (char*)&As[1][0][0] + w * 1024;
  char* lB0 = (char*)&Bs[0][0][0] + w * 1024;
  char* lB1 = (char*)&Bs[1][0][0] + w * 1024;

  for (int k0 = 0; k0 < 1024; k0 += 32) {
    gload16(Ah + gaBase + k0,             lA0);
    gload16(Ah + gaBase + 64 * 1024 + k0, lA0 + 4096);
    gload16(Al + gaBase + k0,             lA1);
    gload16(Al + gaBase + 64 * 1024 + k0, lA1 + 4096);
    gload16(Bh + gbBase + k0,             lB0);
    gload16(Bh + gbBase + 64 * 1024 + k0, lB0 + 4096);
    gload16(Bl + gbBase + k0,             lB1);
    gload16(Bl + gbBase + 64 * 1024 + k0, lB1 + 4096);
    __syncthreads();
    bf16x8 ah[4], am[4], bh[4], bm[4];
#pragma unroll
    for (int i = 0; i < 4; ++i) {
      ah[i] = *reinterpret_cast<const bf16x8*>(&As[0][wr + i * 16 + lr][lg * 8]);
      am[i] = *reinterpret_cast<const bf16x8*>(&As[1][wr + i * 16 + lr][lg * 8]);
      bh[i] = *reinterpret_cast<const bf16x8*>(&Bs[0][wc + i * 16 + lr][lg * 8]);
      bm[i] = *reinterpret_cast<const bf16x8*>(&Bs[1][wc + i * 16 + lr][lg * 8]);
    }
#pragma unroll
    for (int i = 0; i < 4; ++i)
#pragma unroll
      for (int j = 0; j < 4; ++j) {
        acc[i][j] = __builtin_amdgcn_mfma_f32_16x16x32_bf16(ah[i], bh[j], acc[i][j], 0, 0, 0);
        acc[i][j] = __builtin_amdgcn_mfma_f32_16x16x32_bf16(am[i], bh[j], acc[i][j], 0, 0, 0);
        acc[i][j] = __builtin_amdgcn_mfma_f32_16x16x32_bf16(ah[i], bm[j], acc[i][j], 0, 0, 0);
      }
    __syncthreads();
  }
#pragma unroll
  for (int i = 0; i < 4; ++i)
#pragma unroll
    for (int j = 0; j < 4; ++j)
#pragma unroll
      for (int r = 0; r < 4; ++r) {
        int row = m0 + wr + i * 16 + lg * 4 + r;
        int col = n0 + wc + j * 16 + lr;
        float v = acc[i][j][r];
        unsigned short hh = f2bf(v);
        unsigned short ll = f2bf(v - bf2f(hh));
        size_t o = (size_t)row * 4096 + col;
        Qh[o] = hh; Ql[o] = ll;
      }
}

// ---- fused GEMM2 + double softmax + head-mean (v3) -------------------------
// block: 512 thr (8 waves), 32 q2-rows, full N=2048; wave w owns cols
// [w*256, w*256+256). q in frag-major LDS (conflict-free ds_read_b128);
// K streamed from tiled global layout; depth-4 prefetch pipeline with
// HAND-NAMED slot registers (kh0..3/kl0..3) so no scratch is possible.
#define MFMA_BF16(a, b, c) __builtin_amdgcn_mfma_f32_16x16x32_bf16(a, b, c, 0, 0, 0)

// one j-step: 6 MFMAs on slot, then reload the slot (if PF) from pH/pL+OFF
#define JSTEP(J, SLOT, PF, OFF)                                   \
  acc[0][J] = MFMA_BF16(ah0, kh##SLOT, acc[0][J]);                \
  acc[1][J] = MFMA_BF16(ah1, kh##SLOT, acc[1][J]);                \
  acc[0][J] = MFMA_BF16(am0, kh##SLOT, acc[0][J]);                \
  acc[1][J] = MFMA_BF16(am1, kh##SLOT, acc[1][J]);                \
  acc[0][J] = MFMA_BF16(ah0, kl##SLOT, acc[0][J]);                \
  acc[1][J] = MFMA_BF16(ah1, kl##SLOT, acc[1][J]);                \
  if (PF) {                                                       \
    kh##SLOT = *reinterpret_cast<const bf16x8*>(pH + (OFF));      \
    kl##SLOT = *reinterpret_cast<const bf16x8*>(pL + (OFF));      \
  }

// full k0 body: 4 ds_reads + 16 j-steps. Steps 12..15 prefetch next k0.
#define K0BODY(K0, PFTAIL)                                                   \
  do {                                                                      \
    const unsigned short* pH = kwH + (size_t)(K0) * 512;                    \
    const unsigned short* pL = kwL + (size_t)(K0) * 512;                    \
    bf16x8 ah0 = *reinterpret_cast<const bf16x8*>(As + ((K0)) * 512 + l8);  \
    bf16x8 ah1 = *reinterpret_cast<const bf16x8*>(As + (8 + (K0)) * 512 + l8); \
    bf16x8 am0 = *reinterpret_cast<const bf16x8*>(As + (16 + (K0)) * 512 + l8); \
    bf16x8 am1 = *reinterpret_cast<const bf16x8*>(As + (24 + (K0)) * 512 + l8); \
    JSTEP(0, 0, 1, 4 * 4096)                                                \
    JSTEP(1, 1, 1, 5 * 4096)                                                \
    JSTEP(2, 2, 1, 6 * 4096)                                                \
    JSTEP(3, 3, 1, 7 * 4096)                                                \
    JSTEP(4, 0, 1, 8 * 4096)                                                \
    JSTEP(5, 1, 1, 9 * 4096)                                                \
    JSTEP(6, 2, 1, 10 * 4096)                                               \
    JSTEP(7, 3, 1, 11 * 4096)                                               \
    JSTEP(8, 0, 1, 12 * 4096)                                               \
    JSTEP(9, 1, 1, 13 * 4096)                                               \
    JSTEP(10, 2, 1, 14 * 4096)                                              \
    JSTEP(11, 3, 1, 15 * 4096)                                              \
    JSTEP(12, 0, PFTAIL, 0 * 4096 + 512)                                    \
    JSTEP(13, 1, PFTAIL, 1 * 4096 + 512)                                    \
    JSTEP(14, 2, PFTAIL, 2 * 4096 + 512)                                    \
    JSTEP(15, 3, PFTAIL, 3 * 4096 + 512)                                    \
  } while (0)

__global__ __launch_bounds__(512, 2) void k_attn(
    const unsigned short* __restrict__ Qh, const unsigned short* __restrict__ Ql,
    const unsigned short* __restrict__ KtH, const unsigned short* __restrict__ KtL,
    const float* __restrict__ values, const float* __restrict__ cur,
    float* __restrict__ out) {
  // A-frag slot s = plane*16 + mf*8 + k0; each slot: 64 lanes x 16B, linear
  __shared__ unsigned short As[32 * 512];   // 32 KiB
  __shared__ float red[8][32];
  const int tid = threadIdx.x;
  const int w = tid >> 6, l = tid & 63;
  const int lr = l & 15, lg = l >> 4;
  const int r0 = blockIdx.x * 32;   // q2 row base
  const int n0 = w * 256;           // wave col-slice
  const int l8 = l * 8;

  // ---- stage q rows (hi+lo) into frag-major LDS; wave w does slots w*4..+3
#pragma unroll
  for (int qq = 0; qq < 4; ++qq) {
    const int s = w * 4 + qq;
    const int plane = s >> 4, mf = (s >> 3) & 1, k0s = s & 7;
    const unsigned short* src = plane ? Ql : Qh;
    const size_t ga = (size_t)(r0 + mf * 16 + lr) * 256 + k0s * 32 + lg * 8;
    gload16(src + ga, (char*)As + s * 1024);
  }
  __syncthreads();

  // wave-local K base (tiled layout, + per-lane 16B)
  const unsigned short* kwH = KtH + (size_t)w * 65536 + (size_t)l8;
  const unsigned short* kwL = KtL + (size_t)w * 65536 + (size_t)l8;

  f32x4 acc[2][16] = {};
  bf16x8 kh0, kh1, kh2, kh3, kl0, kl1, kl2, kl3;
  // prologue: prefetch (k0=0, j=0..3)
  kh0 = *reinterpret_cast<const bf16x8*>(kwH + 0 * 4096);
  kl0 = *reinterpret_cast<const bf16x8*>(kwL + 0 * 4096);
  kh1 = *reinterpret_cast<const bf16x8*>(kwH + 1 * 4096);
  kl1 = *reinterpret_cast<const bf16x8*>(kwL + 1 * 4096);
  kh2 = *reinterpret_cast<const bf16x8*>(kwH + 2 * 4096);
  kl2 = *reinterpret_cast<const bf16x8*>(kwL + 2 * 4096);
  kh3 = *reinterpret_cast<const bf16x8*>(kwH + 3 * 4096);
  kl3 = *reinterpret_cast<const bf16x8*>(kwL + 3 * 4096);

  for (int k0 = 0; k0 < 7; ++k0) {
    K0BODY(k0, 1);
  }
  K0BODY(7, 0);

  // logits = acc + values[n]
#pragma unroll
  for (int j = 0; j < 16; ++j) {
    float vv = values[n0 + j * 16 + lr];
#pragma unroll
    for (int mf = 0; mf < 2; ++mf)
#pragma unroll
      for (int r = 0; r < 4; ++r) acc[mf][j][r] += vv;
  }

  const int rb = lg * 4;
  // ---------------- first softmax: row max ----------------
  float M1[2][4];
#pragma unroll
  for (int mf = 0; mf < 2; ++mf)
#pragma unroll
    for (int r = 0; r < 4; ++r) {
      float m = acc[mf][0][r];
#pragma unroll
      for (int j = 1; j < 16; ++j) m = fmaxf(m, acc[mf][j][r]);
      m = fmaxf(m, __shfl_xor(m, 1));
      m = fmaxf(m, __shfl_xor(m, 2));
      m = fmaxf(m, __shfl_xor(m, 4));
      m = fmaxf(m, __shfl_xor(m, 8));
      M1[mf][r] = m;
    }
  if (lr == 0) {
#pragma unroll
    for (int mf = 0; mf < 2; ++mf)
#pragma unroll
      for (int r = 0; r < 4; ++r) red[w][mf * 16 + rb + r] = M1[mf][r];
  }
  __syncthreads();
#pragma unroll
  for (int mf = 0; mf < 2; ++mf)
#pragma unroll
    for (int r = 0; r < 4; ++r) {
      float m = red[0][mf * 16 + rb + r];
#pragma unroll
      for (int w2 = 1; w2 < 8; ++w2) m = fmaxf(m, red[w2][mf * 16 + rb + r]);
      M1[mf][r] = m;
    }
  __syncthreads();
  // ---------------- e1 = exp(l - M1), Z1 ----------------
  float Z1[2][4];
#pragma unroll
  for (int mf = 0; mf < 2; ++mf)
#pragma unroll
    for (int r = 0; r < 4; ++r) {
      float z = 0.f;
#pragma unroll
      for (int j = 0; j < 16; ++j) {
        float e = __expf(acc[mf][j][r] - M1[mf][r]);
        acc[mf][j][r] = e;
        z += e;
      }
      z += __shfl_xor(z, 1); z += __shfl_xor(z, 2);
      z += __shfl_xor(z, 4); z += __shfl_xor(z, 8);
      Z1[mf][r] = z;
    }
  if (lr == 0) {
#pragma unroll
    for (int mf = 0; mf < 2; ++mf)
#pragma unroll
      for (int r = 0; r < 4; ++r) red[w][mf * 16 + rb + r] = Z1[mf][r];
  }
  __syncthreads();
#pragma unroll
  for (int mf = 0; mf < 2; ++mf)
#pragma unroll
    for (int r = 0; r < 4; ++r) {
      float z = 0.f;
#pragma unroll
      for (int w2 = 0; w2 < 8; ++w2) z += red[w2][mf * 16 + rb + r];
      Z1[mf][r] = z;
    }
  __syncthreads();
  // ---------------- second softmax (max(logits2) = c/Z1 exactly) -----------
  const float c0 = __expf(cur[(r0 >> 4) + 0]);
  const float c1 = __expf(cur[(r0 >> 4) + 1]);
  float Z2[2][4];
#pragma unroll
  for (int mf = 0; mf < 2; ++mf)
#pragma unroll
    for (int r = 0; r < 4; ++r) {
      float s2 = (mf ? c1 : c0) / Z1[mf][r];
      float z = 0.f;
#pragma unroll
      for (int j = 0; j < 16; ++j) {
        float o = __expf(s2 * (acc[mf][j][r] - 1.0f));
        acc[mf][j][r] = o;
        z += o;
      }
      z += __shfl_xor(z, 1); z += __shfl_xor(z, 2);
      z += __shfl_xor(z, 4); z += __shfl_xor(z, 8);
      Z2[mf][r] = z;
    }
  if (lr == 0) {
#pragma unroll
    for (int mf = 0; mf < 2; ++mf)
#pragma unroll
      for (int r = 0; r < 4; ++r) red[w][mf * 16 + rb + r] = Z2[mf][r];
  }
  __syncthreads();
#pragma unroll
  for (int mf = 0; mf < 2; ++mf)
#pragma unroll
    for (int r = 0; r < 4; ++r) {
      float z = 0.f;
#pragma unroll
      for (int w2 = 0; w2 < 8; ++w2) z += red[w2][mf * 16 + rb + r];
      Z2[mf][r] = z;
    }
  // ---------------- head-mean + write ----------------
  float rz[2][4];
#pragma unroll
  for (int mf = 0; mf < 2; ++mf)
#pragma unroll
    for (int r = 0; r < 4; ++r) rz[mf][r] = 1.0f / (16.0f * Z2[mf][r]);
#pragma unroll
  for (int mf = 0; mf < 2; ++mf)
#pragma unroll
    for (int j = 0; j < 16; ++j) {
      float s = acc[mf][j][0] * rz[mf][0] + acc[mf][j][1] * rz[mf][1] +
                acc[mf][j][2] * rz[mf][2] + acc[mf][j][3] * rz[mf][3];
      s += __shfl_xor(s, 16);
      s += __shfl_xor(s, 32);
      if (l < 16)
        out[(size_t)((r0 >> 4) + mf) * 2048 + n0 + j * 16 + l] = s;
    }
}

// ---------------------------------------------------------------------------
extern "C" void kernel_launch(void* const* d_in, const int* in_sizes, int n_in,
                              void* d_out, int out_size, void* d_ws, size_t ws_size,
                              hipStream_t stream) {
  const float* x    = (const float*)d_in[0];
  const float* cur  = (const float*)d_in[1];
  const float* Wq   = (const float*)d_in[2];
  const float* keys = (const float*)d_in[3];
  const float* vals = (const float*)d_in[4];
  float* out = (float*)d_out;

  char* ws = (char*)d_ws;
  unsigned short* x_hi = (unsigned short*)ws;  ws += (size_t)4096 * 1024 * 2;
  unsigned short* x_lo = (unsigned short*)ws;  ws += (size_t)4096 * 1024 * 2;
  unsigned short* w_hi = (unsigned short*)ws;  ws += (size_t)4096 * 1024 * 2;
  unsigned short* w_lo = (unsigned short*)ws;  ws += (size_t)4096 * 1024 * 2;
  unsigned short* k_hi = (unsigned short*)ws;  ws += (size_t)2048 * 256 * 2;
  unsigned short* k_lo = (unsigned short*)ws;  ws += (size_t)2048 * 256 * 2;
  unsigned short* q_hi = (unsigned short*)ws;  ws += (size_t)4096 * 4096 * 2;
  unsigned short* q_lo = (unsigned short*)ws;

  k_split<<<4096, 256, 0, stream>>>(x, x_hi, x_lo, 4096 * 1024 / 4);
  k_prepk<<<256, 256, 0, stream>>>(keys, k_hi, k_lo);
  k_twq<<<dim3(64, 16), 256, 0, stream>>>(Wq, w_hi, w_lo);
  k_gemm1<<<dim3(32, 32), 256, 0, stream>>>(x_hi, x_lo, w_hi, w_lo, q_hi, q_lo);
  k_attn<<<2048, 512, 0, stream>>>(q_hi, q_lo, k_hi, k_lo, vals, cur, out);
}